// Round 16
// baseline (52.790 us; speedup 1.0000x reference)
//
#include <hip/hip_runtime.h>
#include <math.h>

namespace {

constexpr int D = 32;
constexpr int KOBJ = 1023;          // objects 1..1023 (cluster id 0 = noise)
constexpr float QMIN = 0.01f;
constexpr float PTT = 0.9f;
constexpr float METAETA = 4.0f;

typedef __attribute__((ext_vector_type(8))) short short8;
typedef __attribute__((ext_vector_type(4))) float f32x4;

#define GLOAD_LDS16(g, l)                                              \
  __builtin_amdgcn_global_load_lds(                                    \
      (const __attribute__((address_space(1))) void*)(g),              \
      (__attribute__((address_space(3))) void*)(l), 16, 0, 0)

__device__ inline float waveSum(float v) {
#pragma unroll
  for (int o = 32; o > 0; o >>= 1) v += __shfl_down(v, o, 64);
  return v;
}

// f32 -> bf16 round-to-nearest-even, as raw ushort bits
__device__ inline ushort f2bf(float f) {
  unsigned u = __float_as_uint(f);
  return (ushort)((u + 0x7FFFu + ((u >> 16) & 1u)) >> 16);
}

__device__ inline int keyAlpha(unsigned long long key) {
  return (key != 0ull) ? (int)(0xFFFFFFFFu - (unsigned)(key & 0xFFFFFFFFull)) : 0;
}

// ws: [0,32) acc[8] | [64,8248) keys | alphaArr/qnk/xkbT | qArr/nxArr/attkArr
// acc: 0=attSum 1=repSum 2=noiseSum 3=noiseCnt 4=hitOkCnt 5=cowardSum
__global__ void k_init(int* wsbase) {
  int i = blockIdx.x * 256 + threadIdx.x;
  if (i < 2064) wsbase[i] = 0;
}

__global__ __launch_bounds__(256) void k_hits(
    const float* __restrict__ beta, const float* __restrict__ x,
    const float* __restrict__ pt, const float* __restrict__ eta,
    const int* __restrict__ recon, const int* __restrict__ cidw,
    int N, float* acc, unsigned long long* keys,
    float* __restrict__ qArr, float* __restrict__ nxArr,
    int* __restrict__ attkArr) {
  int t = threadIdx.x;
  int j = blockIdx.x * 256 + t;
  // dtype detect, wave-uniform: int64 cluster_ids (0..1023) => odd words all 0
  int odd = 2 * (t & 127) + 1;
  int ow = (odd < N) ? cidw[odd] : 0;
  int is64 = !__any(ow != 0);
  bool ok = false;
  float nsum = 0.f, ncnt = 0.f;
  if (j < N) {
    int cid = is64 ? cidw[2 * j] : cidw[j];
    float b = beta[j];
    float bc = fminf(fmaxf(b, 0.f), 1.f - 1e-4f);
    float tt = atanhf(bc);
    float q = tt * tt + QMIN;
    ok = (recon[j] > 0) && (pt[j] > PTT) && (fabsf(eta[j]) < METAETA);
    float nx = 0.f;
    const float4* xr = (const float4*)(x + (size_t)j * D);
#pragma unroll
    for (int i2 = 0; i2 < 8; ++i2) {
      float4 v = xr[i2];
      nx += v.x * v.x + v.y * v.y + v.z * v.z + v.w * v.w;
    }
    int attk = (ok && cid >= 1) ? cid : 0;
    qArr[j] = q;
    nxArr[j] = nx;
    attkArr[j] = attk;
    if (cid <= 0) { nsum = b; ncnt = 1.f; }  // noise hit
    if (attk >= 1) {
      unsigned long long key =
          (((unsigned long long)__float_as_uint(q)) << 32) |
          (unsigned long long)(0xFFFFFFFFu - (unsigned)j);
      atomicMax(&keys[attk - 1], key);
    }
  }
  // wave-reduced scalar accumulators (avoid same-address atomic storms)
  float ws2 = waveSum(nsum);
  float ws3 = waveSum(ncnt);
  unsigned long long bal = __ballot(ok);
  if ((t & 63) == 0) {
    if (ws3 != 0.f) { atomicAdd(&acc[2], ws2); atomicAdd(&acc[3], ws3); }
    if (bal) atomicAdd(&acc[4], (float)__popcll(bal));
  }
}

// per object: gather alpha, write qnk (q_k, nx_k) and bf16 embedding in
// k-slice-major layout: xkbT[slice s][object k][8 bf16], slice stride 8192 ushorts
__global__ __launch_bounds__(256, 2) void k_clusters(
    const float* __restrict__ beta, const float* __restrict__ x,
    const unsigned long long* __restrict__ keys,
    const float* __restrict__ qArr, const float* __restrict__ nxArr,
    int* __restrict__ alphaArr, float2* __restrict__ qnk,
    ushort* __restrict__ xkbT, float* acc) {
  int k = blockIdx.x * blockDim.x + threadIdx.x;
  float cw = 0.f;
  if (k < KOBJ) {
    int alpha = keyAlpha(keys[k]);
    alphaArr[k] = alpha;
    qnk[k] = make_float2(qArr[alpha], nxArr[alpha]);
    const float4* s4 = (const float4*)(x + (size_t)alpha * D);
    float4 v[8];
#pragma unroll
    for (int i = 0; i < 8; ++i) v[i] = s4[i];  // batch the row read
#pragma unroll
    for (int s = 0; s < 4; ++s) {
      float4 v0 = v[2 * s], v1 = v[2 * s + 1];
      ushort* dst = xkbT + (size_t)s * 8192 + (size_t)k * 8;
      dst[0] = f2bf(v0.x); dst[1] = f2bf(v0.y);
      dst[2] = f2bf(v0.z); dst[3] = f2bf(v0.w);
      dst[4] = f2bf(v1.x); dst[5] = f2bf(v1.y);
      dst[6] = f2bf(v1.z); dst[7] = f2bf(v1.w);
    }
    cw = 1.f - beta[alpha];
  } else if (k == KOBJ) {  // pad object 1023: never passes d2<1
    qnk[k] = make_float2(0.f, 1e30f);
#pragma unroll
    for (int s = 0; s < 4; ++s) {
      ushort* dst = xkbT + (size_t)s * 8192 + (size_t)k * 8;
#pragma unroll
      for (int e = 0; e < 8; ++e) dst[e] = 0;
    }
  }
  float s = waveSum(cw);
  if ((threadIdx.x & 63) == 0 && s != 0.f) atomicAdd(&acc[5], s);
}

// rep sweep: block tile = 128 rows x 128 objects; 1-D grid, XCD co-location:
// the 8 object-tile blocks sharing rowgroup g get lid%8 == g%8 -> same XCD L2
// -> x rows fetched once per XCD, 7 blocks hit L2.
// Single-drain structure: att gathers are issued+consumed BEFORE the staging
// __syncthreads, so their latency overlaps the global_load_lds drain.
// A = bf16(-2x), C = nx_row + nx_k  =>  MFMA output is d2 directly.
__global__ __launch_bounds__(256) void k_pair(
    const float* __restrict__ x, int N, int rowgroups,
    const float* __restrict__ qArr, const float* __restrict__ nxArr,
    const int* __restrict__ attkArr, const int* __restrict__ alphaArr,
    const float2* __restrict__ qnk, const ushort* __restrict__ xkbT,
    float* acc) {
  __shared__ char lds[8192 + 1024 + 64];  // B panel | qnk tile | reduce slots
  float* redS = (float*)(lds + 9216);
  int t = threadIdx.x;
  int wv = t >> 6;
  int ln = t & 63;

  int lid = blockIdx.x;
  int g = (lid >> 6) * 8 + (lid & 7);   // rowgroup (XCD-co-located sharers)
  int ot = (lid >> 3) & 7;              // object tile: objects [ot*128, +128)
  if (g >= rowgroups) return;
  int ob = ot * 128;
  int rowbase = g * 128;

  // ---- stage 9 KB via global_load_lds: chunk c -> lds[c*1024], 1 KB/chunk
  for (int c = wv; c < 9; c += 4) {  // wave-uniform lds base per chunk
    const char* src;
    if (c < 8)  // B panel: slice c>>1, sub-chunk c&1
      src = (const char*)xkbT + (c >> 1) * 16384 + ob * 16 + (c & 1) * 1024;
    else        // qnk tile (1 KB)
      src = (const char*)qnk + ob * 8;
    GLOAD_LDS16(src + ln * 16, lds + c * 1024);
  }

  int lr = ln & 15;                 // A row / B,C col selector
  int lk = ln >> 4;                 // k-slice / acc-row-group selector
  int wrow = rowbase + wv * 32;     // this wave's 32-row tile base

  // A fragments: bf16(-2 * x_row), two 16-row tiles per wave
  short8 am2[2];
#pragma unroll
  for (int rt = 0; rt < 2; ++rt) {
    int row = min(wrow + rt * 16 + lr, N - 1);  // clamp; pads disabled via nxr
    const float* p = x + (size_t)row * D + lk * 8;
    float4 v0 = *(const float4*)p;
    float4 v1 = *(const float4*)(p + 4);
    short8 a;
    a[0] = (short)f2bf(-2.f * v0.x); a[1] = (short)f2bf(-2.f * v0.y);
    a[2] = (short)f2bf(-2.f * v0.z); a[3] = (short)f2bf(-2.f * v0.w);
    a[4] = (short)f2bf(-2.f * v1.x); a[5] = (short)f2bf(-2.f * v1.y);
    a[6] = (short)f2bf(-2.f * v1.z); a[7] = (short)f2bf(-2.f * v1.w);
    am2[rt] = a;
  }
  // per-acc-row norms and charges; C-row i of tile rt = wrow + rt*16 + lk*4 + i
  float nxr[2][4], qrow[2][4];
#pragma unroll
  for (int rt = 0; rt < 2; ++rt)
#pragma unroll
    for (int i = 0; i < 4; ++i) {
      int row = wrow + rt * 16 + lk * 4 + i;
      int rc = min(row, N - 1);
      nxr[rt][i] = (row < N) ? nxArr[rc] : 1e37f;
      qrow[rt][i] = (row < N) ? qArr[rc] : 0.f;
    }

  // ---- exact f32 attractive term (ot==0 blocks; 2 threads per row) ----
  // Placed BEFORE the staging sync: its gather latency overlaps the
  // global_load_lds drain (single vmcnt(0) serves both).
  float attc = 0.f, repSub = 0.f;
  if (ot == 0) {
    int j = rowbase + (t >> 1);
    int qt = t & 1;
    if (j < N) {
      int attk = attkArr[j];
      if (attk >= 1) {
        int k0 = attk - 1;
        int alpha = alphaArr[k0];
        float2 qn = qnk[k0];  // exact f32 (q_k, nx_k)
        const float4* xj = (const float4*)(x + (size_t)j * D + qt * 16);
        const float4* xk = (const float4*)(x + (size_t)alpha * D + qt * 16);
        float dot = 0.f;
#pragma unroll
        for (int i = 0; i < 4; ++i) {
          float4 a = xj[i], bb = xk[i];
          dot += a.x * bb.x + a.y * bb.y + a.z * bb.z + a.w * bb.w;
        }
        dot += __shfl_xor(dot, 1, 2);
        if (qt == 0) {
          float d2 = nxArr[j] + qn.y - 2.f * dot;
          float w = qArr[j] * qn.x;
          attc = w * fmaxf(d2, 1e-12f);
          if (d2 < 1.f)  // att pair is counted by the rep sweep: subtract
            repSub = w * (1.f - sqrtf(fmaxf(d2, 1e-12f)));
        }
      }
    }
  }
  __syncthreads();  // drains global_load_lds (att loads already consumed)

  const float2* qnkS = (const float2*)(lds + 8192);
  float rep = 0.f;
#pragma unroll
  for (int tt = 0; tt < 8; ++tt) {
    int o = tt * 16 + lr;           // local object (B col = lr)
    short8 b = *(const short8*)(lds + lk * 2048 + o * 16);
    float2 qn = qnkS[o];
    float nk = qn.y;
    f32x4 c0 = {nxr[0][0] + nk, nxr[0][1] + nk, nxr[0][2] + nk, nxr[0][3] + nk};
    f32x4 c1 = {nxr[1][0] + nk, nxr[1][1] + nk, nxr[1][2] + nk, nxr[1][3] + nk};
    f32x4 s0 = __builtin_amdgcn_mfma_f32_16x16x32_bf16(am2[0], b, c0, 0, 0, 0);
    f32x4 s1 = __builtin_amdgcn_mfma_f32_16x16x32_bf16(am2[1], b, c1, 0, 0, 0);
    float m = fminf(fminf(fminf(s0[0], s0[1]), fminf(s0[2], s0[3])),
                    fminf(fminf(s1[0], s1[1]), fminf(s1[2], s1[3])));
    if (__any(m < 1.f)) {  // rare: some pair within unit distance
      float qk = qn.x;
#pragma unroll
      for (int i = 0; i < 4; ++i) {
        if (s0[i] < 1.f)
          rep += qrow[0][i] * qk * (1.f - sqrtf(fmaxf(s0[i], 1e-12f)));
        if (s1[i] < 1.f)
          rep += qrow[1][i] * qk * (1.f - sqrtf(fmaxf(s1[i], 1e-12f)));
      }
    }
  }

  // ---- block reduction: one atomic set per block ----
  float sw = waveSum(rep);
  float sa = waveSum(attc);
  float sr = waveSum(repSub);
  if (ln == 0) { redS[wv] = sw; redS[4 + wv] = sa; redS[8 + wv] = sr; }
  __syncthreads();
  if (t == 0) {
    float tot = (redS[0] + redS[1]) + (redS[2] + redS[3]);
    float ta = (redS[4] + redS[5]) + (redS[6] + redS[7]);
    float tr = (redS[8] + redS[9]) + (redS[10] + redS[11]);
    if (tot != tr) atomicAdd(&acc[1], tot - tr);
    if (ta != 0.f) atomicAdd(&acc[0], ta);
  }
}

__global__ void k_final(const float* __restrict__ acc, int N, float* out) {
  if (threadIdx.x == 0 && blockIdx.x == 0) {
    double attSum = acc[0], repSum = acc[1], noiseSum = acc[2];
    double noiseCnt = acc[3], okCnt = acc[4], cowardSum = acc[5];
    double norm_att = 1e-9 + okCnt - (double)KOBJ;
    double norm_rep = 1e-9 + (double)(KOBJ - 1) * (double)N;
    double v_att = attSum / norm_att;
    double v_rep = repSum / norm_rep;
    double l_coward = cowardSum / (double)KOBJ;
    double l_noise = noiseSum / fmax(noiseCnt, 1.0);
    out[0] = (float)(v_att + 1.0 * v_rep + 0.1 * l_noise + 0.1 * l_coward);
  }
}

}  // namespace

extern "C" void kernel_launch(void* const* d_in, const int* in_sizes, int n_in,
                              void* d_out, int out_size, void* d_ws, size_t ws_size,
                              hipStream_t stream) {
  const float* beta = (const float*)d_in[0];
  const float* x = (const float*)d_in[1];
  const float* pt = (const float*)d_in[2];
  const float* eta = (const float*)d_in[3];
  const int* recon = (const int*)d_in[4];
  const int* cidw = (const int*)d_in[5];  // int32 or int64 layout, device-detected
  int N = in_sizes[0];
  float* out = (float*)d_out;

  char* w = (char*)d_ws;
  float* acc = (float*)w;                                   // 8 f32
  unsigned long long* keys = (unsigned long long*)(w + 64); // 1023*8
  int* alphaArr = (int*)(w + 8256);                         // 1023*4
  float2* qnk = (float2*)(w + 12352);                       // 1024*8
  ushort* xkbT = (ushort*)(w + 20544);                      // [4][1024][8] = 65536 B
  float* qArr = (float*)(w + 86080);                        // N*4
  float* nxArr = (float*)(w + 86080 + (size_t)N * 4);       // N*4
  int* attkArr = (int*)(w + 86080 + (size_t)N * 8);         // N*4

  int nbN = (N + 255) / 256;
  int rowgroups = (N + 127) / 128;
  int npair = ((rowgroups + 7) / 8) * 64;  // 8 blocks per rowgroup, XCD-packed

  k_init<<<9, 256, 0, stream>>>((int*)w);
  k_hits<<<nbN, 256, 0, stream>>>(beta, x, pt, eta, recon, cidw, N,
                                  acc, keys, qArr, nxArr, attkArr);
  k_clusters<<<4, 256, 0, stream>>>(beta, x, keys, qArr, nxArr,
                                    alphaArr, qnk, xkbT, acc);
  k_pair<<<npair, 256, 0, stream>>>(x, N, rowgroups, qArr, nxArr, attkArr,
                                    alphaArr, qnk, xkbT, acc);
  k_final<<<1, 64, 0, stream>>>(acc, N, out);
}

// Round 17
// 51.052 us; speedup vs baseline: 1.0340x; 1.0340x over previous
//
#include <hip/hip_runtime.h>
#include <math.h>

namespace {

constexpr int D = 32;
constexpr int KOBJ = 1023;          // objects 1..1023 (cluster id 0 = noise)
constexpr float QMIN = 0.01f;
constexpr float PTT = 0.9f;
constexpr float METAETA = 4.0f;

typedef __attribute__((ext_vector_type(8))) short short8;
typedef __attribute__((ext_vector_type(4))) float f32x4;

#define GLOAD_LDS16(g, l)                                              \
  __builtin_amdgcn_global_load_lds(                                    \
      (const __attribute__((address_space(1))) void*)(g),              \
      (__attribute__((address_space(3))) void*)(l), 16, 0, 0)

__device__ inline float waveSum(float v) {
#pragma unroll
  for (int o = 32; o > 0; o >>= 1) v += __shfl_down(v, o, 64);
  return v;
}

// f32 -> bf16 round-to-nearest-even, as raw ushort bits
__device__ inline ushort f2bf(float f) {
  unsigned u = __float_as_uint(f);
  return (ushort)((u + 0x7FFFu + ((u >> 16) & 1u)) >> 16);
}

__device__ inline int keyAlpha(unsigned long long key) {
  return (key != 0ull) ? (int)(0xFFFFFFFFu - (unsigned)(key & 0xFFFFFFFFull)) : 0;
}

// ws: [0,32) acc[8] | [64,8248) keys | alphaArr/qnk/xkbT | qArr/nxArr/attkArr
// acc: 0=attSum 1=repSum 2=noiseSum 3=noiseCnt 4=hitOkCnt 5=cowardSum
__global__ void k_init(int* wsbase) {
  int i = blockIdx.x * 256 + threadIdx.x;
  if (i < 2064) wsbase[i] = 0;
}

__global__ __launch_bounds__(256) void k_hits(
    const float* __restrict__ beta, const float* __restrict__ x,
    const float* __restrict__ pt, const float* __restrict__ eta,
    const int* __restrict__ recon, const int* __restrict__ cidw,
    int N, float* acc, unsigned long long* keys,
    float* __restrict__ qArr, float* __restrict__ nxArr,
    int* __restrict__ attkArr) {
  int t = threadIdx.x;
  int j = blockIdx.x * 256 + t;
  // dtype detect, wave-uniform: int64 cluster_ids (0..1023) => odd words all 0
  int odd = 2 * (t & 127) + 1;
  int ow = (odd < N) ? cidw[odd] : 0;
  int is64 = !__any(ow != 0);
  bool ok = false;
  float nsum = 0.f, ncnt = 0.f;
  if (j < N) {
    int cid = is64 ? cidw[2 * j] : cidw[j];
    float b = beta[j];
    float bc = fminf(fmaxf(b, 0.f), 1.f - 1e-4f);
    float tt = atanhf(bc);
    float q = tt * tt + QMIN;
    ok = (recon[j] > 0) && (pt[j] > PTT) && (fabsf(eta[j]) < METAETA);
    float nx = 0.f;
    const float4* xr = (const float4*)(x + (size_t)j * D);
#pragma unroll
    for (int i2 = 0; i2 < 8; ++i2) {
      float4 v = xr[i2];
      nx += v.x * v.x + v.y * v.y + v.z * v.z + v.w * v.w;
    }
    int attk = (ok && cid >= 1) ? cid : 0;
    qArr[j] = q;
    nxArr[j] = nx;
    attkArr[j] = attk;
    if (cid <= 0) { nsum = b; ncnt = 1.f; }  // noise hit
    if (attk >= 1) {
      unsigned long long key =
          (((unsigned long long)__float_as_uint(q)) << 32) |
          (unsigned long long)(0xFFFFFFFFu - (unsigned)j);
      atomicMax(&keys[attk - 1], key);
    }
  }
  // wave-reduced scalar accumulators (avoid same-address atomic storms)
  float ws2 = waveSum(nsum);
  float ws3 = waveSum(ncnt);
  unsigned long long bal = __ballot(ok);
  if ((t & 63) == 0) {
    if (ws3 != 0.f) { atomicAdd(&acc[2], ws2); atomicAdd(&acc[3], ws3); }
    if (bal) atomicAdd(&acc[4], (float)__popcll(bal));
  }
}

// per object: gather alpha, write qnk (q_k, nx_k) and bf16 embedding in
// k-slice-major layout: xkbT[slice s][object k][8 bf16], slice stride 8192 ushorts
__global__ __launch_bounds__(256, 2) void k_clusters(
    const float* __restrict__ beta, const float* __restrict__ x,
    const unsigned long long* __restrict__ keys,
    const float* __restrict__ qArr, const float* __restrict__ nxArr,
    int* __restrict__ alphaArr, float2* __restrict__ qnk,
    ushort* __restrict__ xkbT, float* acc) {
  int k = blockIdx.x * blockDim.x + threadIdx.x;
  float cw = 0.f;
  if (k < KOBJ) {
    int alpha = keyAlpha(keys[k]);
    alphaArr[k] = alpha;
    qnk[k] = make_float2(qArr[alpha], nxArr[alpha]);
    const float4* s4 = (const float4*)(x + (size_t)alpha * D);
    float4 v[8];
#pragma unroll
    for (int i = 0; i < 8; ++i) v[i] = s4[i];  // batch the row read
#pragma unroll
    for (int s = 0; s < 4; ++s) {
      float4 v0 = v[2 * s], v1 = v[2 * s + 1];
      ushort* dst = xkbT + (size_t)s * 8192 + (size_t)k * 8;
      dst[0] = f2bf(v0.x); dst[1] = f2bf(v0.y);
      dst[2] = f2bf(v0.z); dst[3] = f2bf(v0.w);
      dst[4] = f2bf(v1.x); dst[5] = f2bf(v1.y);
      dst[6] = f2bf(v1.z); dst[7] = f2bf(v1.w);
    }
    cw = 1.f - beta[alpha];
  } else if (k == KOBJ) {  // pad object 1023: never passes d2<1
    qnk[k] = make_float2(0.f, 1e30f);
#pragma unroll
    for (int s = 0; s < 4; ++s) {
      ushort* dst = xkbT + (size_t)s * 8192 + (size_t)k * 8;
#pragma unroll
      for (int e = 0; e < 8; ++e) dst[e] = 0;
    }
  }
  float s = waveSum(cw);
  if ((threadIdx.x & 63) == 0 && s != 0.f) atomicAdd(&acc[5], s);
}

// rep sweep: block tile = 128 rows x 256 objects; 1-D grid with XCD
// co-location swizzle: lid = (g/8)*32 + m*8 + g%8, so the 4 object-tile
// blocks (m=0..3) sharing rowgroup g have equal lid%8 -> same XCD under
// round-robin dispatch -> x rows fetched to that L2 once, 3 blocks hit L2.
// Panel+qnk staged via global_load_lds; inner loop LDS+MFMA+fmin; rare
// __any branch does the sqrt. A = bf16(-2x), C = nx_row + nx_k => MFMA
// output is d2 directly.
__global__ __launch_bounds__(256) void k_pair(
    const float* __restrict__ x, int N, int rowgroups,
    const float* __restrict__ qArr, const float* __restrict__ nxArr,
    const int* __restrict__ attkArr, const int* __restrict__ alphaArr,
    const float2* __restrict__ qnk, const ushort* __restrict__ xkbT,
    float* acc) {
  __shared__ char lds[16384 + 2048 + 64];  // B panel | qnk tile | reduce slots
  float* redS = (float*)(lds + 18432);
  int t = threadIdx.x;
  int wv = t >> 6;
  int ln = t & 63;

  int lid = blockIdx.x;
  int g = (lid >> 5) * 8 + (lid & 7);   // rowgroup
  int ot = (lid >> 3) & 3;              // object tile: objects [ot*256, +256)
  if (g >= rowgroups) return;
  int ob = ot * 256;
  int rowbase = g * 128;

  // ---- stage 18 KB via global_load_lds: chunk c -> lds[c*1024], 1 KB/chunk
  for (int c = wv; c < 18; c += 4) {  // wave-uniform lds base per chunk
    const char* src;
    if (c < 16)  // B panel: slice c>>2, sub-chunk c&3
      src = (const char*)xkbT + (c >> 2) * 16384 + ob * 16 + (c & 3) * 1024;
    else         // qnk tile (2 KB)
      src = (const char*)qnk + ob * 8 + (c - 16) * 1024;
    GLOAD_LDS16(src + ln * 16, lds + c * 1024);
  }

  int lr = ln & 15;                 // A row / B,C col selector
  int lk = ln >> 4;                 // k-slice / acc-row-group selector
  int wrow = rowbase + wv * 32;     // this wave's 32-row tile base

  // A fragments: bf16(-2 * x_row), two 16-row tiles per wave
  short8 am2[2];
#pragma unroll
  for (int rt = 0; rt < 2; ++rt) {
    int row = min(wrow + rt * 16 + lr, N - 1);  // clamp; pads disabled via nxr
    const float* p = x + (size_t)row * D + lk * 8;
    float4 v0 = *(const float4*)p;
    float4 v1 = *(const float4*)(p + 4);
    short8 a;
    a[0] = (short)f2bf(-2.f * v0.x); a[1] = (short)f2bf(-2.f * v0.y);
    a[2] = (short)f2bf(-2.f * v0.z); a[3] = (short)f2bf(-2.f * v0.w);
    a[4] = (short)f2bf(-2.f * v1.x); a[5] = (short)f2bf(-2.f * v1.y);
    a[6] = (short)f2bf(-2.f * v1.z); a[7] = (short)f2bf(-2.f * v1.w);
    am2[rt] = a;
  }
  // per-acc-row norms and charges; C-row i of tile rt = wrow + rt*16 + lk*4 + i
  float nxr[2][4], qrow[2][4];
#pragma unroll
  for (int rt = 0; rt < 2; ++rt)
#pragma unroll
    for (int i = 0; i < 4; ++i) {
      int row = wrow + rt * 16 + lk * 4 + i;
      int rc = min(row, N - 1);
      nxr[rt][i] = (row < N) ? nxArr[rc] : 1e37f;
      qrow[rt][i] = (row < N) ? qArr[rc] : 0.f;
    }
  __syncthreads();  // compiler inserts vmcnt(0) drain for global_load_lds

  const float2* qnkS = (const float2*)(lds + 16384);
  float rep = 0.f;
#pragma unroll 4
  for (int tt = 0; tt < 16; ++tt) {
    int o = tt * 16 + lr;           // local object (B col = lr)
    short8 b = *(const short8*)(lds + lk * 4096 + o * 16);
    float2 qn = qnkS[o];
    float nk = qn.y;
    f32x4 c0 = {nxr[0][0] + nk, nxr[0][1] + nk, nxr[0][2] + nk, nxr[0][3] + nk};
    f32x4 c1 = {nxr[1][0] + nk, nxr[1][1] + nk, nxr[1][2] + nk, nxr[1][3] + nk};
    f32x4 s0 = __builtin_amdgcn_mfma_f32_16x16x32_bf16(am2[0], b, c0, 0, 0, 0);
    f32x4 s1 = __builtin_amdgcn_mfma_f32_16x16x32_bf16(am2[1], b, c1, 0, 0, 0);
    float m = fminf(fminf(fminf(s0[0], s0[1]), fminf(s0[2], s0[3])),
                    fminf(fminf(s1[0], s1[1]), fminf(s1[2], s1[3])));
    if (__any(m < 1.f)) {  // rare: some pair within unit distance
      float qk = qn.x;
#pragma unroll
      for (int i = 0; i < 4; ++i) {
        if (s0[i] < 1.f)
          rep += qrow[0][i] * qk * (1.f - sqrtf(fmaxf(s0[i], 1e-12f)));
        if (s1[i] < 1.f)
          rep += qrow[1][i] * qk * (1.f - sqrtf(fmaxf(s1[i], 1e-12f)));
      }
    }
  }

  // ---- exact f32 attractive term (ot==0 blocks; 2 threads per row) ----
  float attc = 0.f, repSub = 0.f;
  if (ot == 0) {
    int j = rowbase + (t >> 1);
    int qt = t & 1;
    if (j < N) {
      int attk = attkArr[j];
      if (attk >= 1) {
        int k0 = attk - 1;
        int alpha = alphaArr[k0];
        float2 qn = qnk[k0];  // exact f32 (q_k, nx_k)
        const float4* xj = (const float4*)(x + (size_t)j * D + qt * 16);
        const float4* xk = (const float4*)(x + (size_t)alpha * D + qt * 16);
        float dot = 0.f;
#pragma unroll
        for (int i = 0; i < 4; ++i) {
          float4 a = xj[i], bb = xk[i];
          dot += a.x * bb.x + a.y * bb.y + a.z * bb.z + a.w * bb.w;
        }
        dot += __shfl_xor(dot, 1, 2);
        if (qt == 0) {
          float d2 = nxArr[j] + qn.y - 2.f * dot;
          float w = qArr[j] * qn.x;
          attc = w * fmaxf(d2, 1e-12f);
          if (d2 < 1.f)  // att pair was counted by the rep sweep: subtract
            repSub = w * (1.f - sqrtf(fmaxf(d2, 1e-12f)));
        }
      }
    }
  }

  // ---- block reduction: one atomic set per block ----
  float sw = waveSum(rep);
  float sa = waveSum(attc);
  float sr = waveSum(repSub);
  if (ln == 0) { redS[wv] = sw; redS[4 + wv] = sa; redS[8 + wv] = sr; }
  __syncthreads();
  if (t == 0) {
    float tot = (redS[0] + redS[1]) + (redS[2] + redS[3]);
    float ta = (redS[4] + redS[5]) + (redS[6] + redS[7]);
    float tr = (redS[8] + redS[9]) + (redS[10] + redS[11]);
    if (tot != tr) atomicAdd(&acc[1], tot - tr);
    if (ta != 0.f) atomicAdd(&acc[0], ta);
  }
}

__global__ void k_final(const float* __restrict__ acc, int N, float* out) {
  if (threadIdx.x == 0 && blockIdx.x == 0) {
    double attSum = acc[0], repSum = acc[1], noiseSum = acc[2];
    double noiseCnt = acc[3], okCnt = acc[4], cowardSum = acc[5];
    double norm_att = 1e-9 + okCnt - (double)KOBJ;
    double norm_rep = 1e-9 + (double)(KOBJ - 1) * (double)N;
    double v_att = attSum / norm_att;
    double v_rep = repSum / norm_rep;
    double l_coward = cowardSum / (double)KOBJ;
    double l_noise = noiseSum / fmax(noiseCnt, 1.0);
    out[0] = (float)(v_att + 1.0 * v_rep + 0.1 * l_noise + 0.1 * l_coward);
  }
}

}  // namespace

extern "C" void kernel_launch(void* const* d_in, const int* in_sizes, int n_in,
                              void* d_out, int out_size, void* d_ws, size_t ws_size,
                              hipStream_t stream) {
  const float* beta = (const float*)d_in[0];
  const float* x = (const float*)d_in[1];
  const float* pt = (const float*)d_in[2];
  const float* eta = (const float*)d_in[3];
  const int* recon = (const int*)d_in[4];
  const int* cidw = (const int*)d_in[5];  // int32 or int64 layout, device-detected
  int N = in_sizes[0];
  float* out = (float*)d_out;

  char* w = (char*)d_ws;
  float* acc = (float*)w;                                   // 8 f32
  unsigned long long* keys = (unsigned long long*)(w + 64); // 1023*8
  int* alphaArr = (int*)(w + 8256);                         // 1023*4
  float2* qnk = (float2*)(w + 12352);                       // 1024*8
  ushort* xkbT = (ushort*)(w + 20544);                      // [4][1024][8] = 65536 B
  float* qArr = (float*)(w + 86080);                        // N*4
  float* nxArr = (float*)(w + 86080 + (size_t)N * 4);       // N*4
  int* attkArr = (int*)(w + 86080 + (size_t)N * 8);         // N*4

  int nbN = (N + 255) / 256;
  int rowgroups = (N + 127) / 128;
  int npair = ((rowgroups + 7) / 8) * 32;  // 4 blocks per rowgroup, XCD-packed

  k_init<<<9, 256, 0, stream>>>((int*)w);
  k_hits<<<nbN, 256, 0, stream>>>(beta, x, pt, eta, recon, cidw, N,
                                  acc, keys, qArr, nxArr, attkArr);
  k_clusters<<<4, 256, 0, stream>>>(beta, x, keys, qArr, nxArr,
                                    alphaArr, qnk, xkbT, acc);
  k_pair<<<npair, 256, 0, stream>>>(x, N, rowgroups, qArr, nxArr, attkArr,
                                    alphaArr, qnk, xkbT, acc);
  k_final<<<1, 64, 0, stream>>>(acc, N, out);
}